// Round 7
// baseline (309.688 us; speedup 1.0000x reference)
//
#include <hip/hip_runtime.h>

#define BLOCK  256
#define NGRAPH 8
#define TE     2048   // float4 elements per tile (512 rows); 32 KB x + 32 KB t in LDS
#define NSLOT  8      // accumulation slots (separate cachelines) to spread atomics

// d_ws layout: float[NSLOT][16]; slot s: [0..7] = per-graph dots, [8] = base

#define GPTR(p) ((const __attribute__((address_space(1))) void*)(p))
#define LPTR(p) ((__attribute__((address_space(3))) void*)(p))

__global__ __launch_bounds__(BLOCK) void reduce_kernel(
    const float4* __restrict__ x4,
    const float4* __restrict__ t4,
    const int*    __restrict__ batch,
    float* __restrict__ g_acc,
    int M /* = N*4 float4 elements */)
{
    __shared__ float4 sx[TE];   // 32 KB
    __shared__ float4 st[TE];   // 32 KB

    const int tid  = threadIdx.x;
    const int lane = tid & 63;
    const int w    = tid >> 6;           // wave id 0..3

    const int elo = (int)blockIdx.x * TE;          // contiguous tile per block
    const int ehi = min(elo + TE, M);

    // batch is sorted: same graph at both ends -> whole tile is one graph.
    const int g0 = batch[elo >> 2];
    const int g1 = batch[(ehi - 1) >> 2];

    float* slot = g_acc + ((int)blockIdx.x & (NSLOT - 1)) * 16;

    if (g0 == g1 && ehi == elo + TE) {
        // ---- async DMA stage: 16 fire-and-forget instructions per wave ----
        // No destination VGPRs -> the compiler CANNOT re-serialize this.
        // Each instruction stages 64 lanes x 16 B = 1 KB. 16 KB in flight/wave.
        const float4* gx = x4 + elo + w * 512 + lane;
        const float4* gt = t4 + elo + w * 512 + lane;
        #pragma unroll
        for (int k = 0; k < 8; ++k)
            __builtin_amdgcn_global_load_lds(GPTR(gx + k * 64),
                                             LPTR(&sx[w * 512 + k * 64]), 16, 0, 0);
        #pragma unroll
        for (int k = 0; k < 8; ++k)
            __builtin_amdgcn_global_load_lds(GPTR(gt + k * 64),
                                             LPTR(&st[w * 512 + k * 64]), 16, 0, 0);
        __syncthreads();   // s_waitcnt vmcnt(0) + barrier: tile fully staged

        // ---- compute phase: LDS -> registers, 2 independent chains ----
        float d0 = 0.f, d1 = 0.f, b0 = 0.f, b1 = 0.f;
        #pragma unroll
        for (int j = 0; j < 8; j += 2) {
            const float4 a0 = sx[tid + (j    ) * BLOCK];
            const float4 c0 = st[tid + (j    ) * BLOCK];
            const float4 a1 = sx[tid + (j + 1) * BLOCK];
            const float4 c1 = st[tid + (j + 1) * BLOCK];
            d0 += a0.x*c0.x + a0.y*c0.y + a0.z*c0.z + a0.w*c0.w;
            d1 += a1.x*c1.x + a1.y*c1.y + a1.z*c1.z + a1.w*c1.w;
            b0 += a0.x*a0.x + a0.y*a0.y + a0.z*a0.z + a0.w*a0.w
                + c0.x*c0.x + c0.y*c0.y + c0.z*c0.z + c0.w*c0.w;
            b1 += a1.x*a1.x + a1.y*a1.y + a1.z*a1.z + a1.w*a1.w
                + c1.x*c1.x + c1.y*c1.y + c1.z*c1.z + c1.w*c1.w;
        }
        float dot = d0 + d1, base = b0 + b1;

        #pragma unroll
        for (int off = 32; off > 0; off >>= 1) {
            dot  += __shfl_xor(dot,  off, 64);
            base += __shfl_xor(base, off, 64);
        }
        if (lane == 0) {
            atomicAdd(&slot[g0],     dot);
            atomicAdd(&slot[NGRAPH], base);
        }
    } else {
        // ---- rare path: graph-boundary tile (<=7) or partial tail tile (1) ----
        float acc[NGRAPH];
        #pragma unroll
        for (int i = 0; i < NGRAPH; ++i) acc[i] = 0.0f;
        float base = 0.0f;
        for (int e = elo + tid; e < ehi; e += BLOCK) {
            const float4 a = x4[e];
            const float4 c = t4[e];
            const int    b = batch[e >> 2];
            base += a.x*a.x + a.y*a.y + a.z*a.z + a.w*a.w
                  + c.x*c.x + c.y*c.y + c.z*c.z + c.w*c.w;
            const float d = a.x*c.x + a.y*c.y + a.z*c.z + a.w*c.w;
            #pragma unroll
            for (int i = 0; i < NGRAPH; ++i)
                acc[i] += (b == i) ? d : 0.0f;
        }
        #pragma unroll
        for (int i = 0; i <= NGRAPH; ++i) {
            float v = (i < NGRAPH) ? acc[i] : base;
            #pragma unroll
            for (int off = 32; off > 0; off >>= 1)
                v += __shfl_xor(v, off, 64);
            if (lane == 0)
                atomicAdd(&slot[i], v);
        }
    }
}

__global__ void finalize_kernel(const float* __restrict__ g_acc,
                                float* __restrict__ out)
{
    if (threadIdx.x == 0) {
        float dots[NGRAPH];
        #pragma unroll
        for (int i = 0; i < NGRAPH; ++i) dots[i] = 0.0f;
        float base = 0.0f;
        for (int s = 0; s < NSLOT; ++s) {
            #pragma unroll
            for (int i = 0; i < NGRAPH; ++i) dots[i] += g_acc[s * 16 + i];
            base += g_acc[s * 16 + NGRAPH];
        }
        float sum = 0.0f;
        #pragma unroll
        for (int i = 0; i < NGRAPH; ++i) sum += fabsf(dots[i]);
        out[0] = base - 2.0f * sum;
    }
}

extern "C" void kernel_launch(void* const* d_in, const int* in_sizes, int n_in,
                              void* d_out, int out_size, void* d_ws, size_t ws_size,
                              hipStream_t stream) {
    const float* inp   = (const float*)d_in[0];
    const float* tgt   = (const float*)d_in[1];
    const int*   batch = (const int*)d_in[2];
    // d_in[3] is batch_size == 8 (compile-time NGRAPH)

    const long long Nrows = (long long)in_sizes[0] / 16;  // F = 16
    const int       M     = (int)(Nrows * 4);             // float4 elements

    float* g_acc = (float*)d_ws;
    hipMemsetAsync(g_acc, 0, NSLOT * 16 * sizeof(float), stream);

    const int nblocks = (M + TE - 1) / TE;                // one tile per block
    reduce_kernel<<<nblocks, BLOCK, 0, stream>>>(
        (const float4*)inp, (const float4*)tgt, batch, g_acc, M);

    finalize_kernel<<<1, 64, 0, stream>>>(g_acc, (float*)d_out);
}

// Round 9
// 256.255 us; speedup vs baseline: 1.2085x; 1.2085x over previous
//
#include <hip/hip_runtime.h>

#define BLOCK  256
#define NGRAPH 8
#define EBLK   2048   // float4 elements per tile (= 512 rows); 1 tile per block
#define NSLOT  8      // accumulation slots (separate cachelines) to spread atomics

// d_ws layout: float[NSLOT][16]; slot s: [0..7] = per-graph dots, [8] = base

typedef float f32x4 __attribute__((ext_vector_type(4)));

static __device__ __forceinline__ float4 ldnt(const float4* p) {
    // non-temporal: sets the nt cache bit -> no L1 allocation for a
    // single-pass stream; frees the L1 fill path.
    f32x4 v = __builtin_nontemporal_load((const f32x4*)p);
    return make_float4(v.x, v.y, v.z, v.w);
}

__global__ __launch_bounds__(BLOCK) void reduce_kernel(
    const float4* __restrict__ x4,
    const float4* __restrict__ t4,
    const int*    __restrict__ batch,
    float* __restrict__ g_acc,
    int M /* = N*4 float4 elements */)
{
    __shared__ float s_acc[NGRAPH + 1];
    const int tid = threadIdx.x;
    if (tid < NGRAPH + 1) s_acc[tid] = 0.0f;
    __syncthreads();

    const int elo = (int)blockIdx.x * EBLK;          // contiguous tile per block
    const int ehi = min(elo + EBLK, M);

    // batch is sorted: same graph at both ends -> whole tile is one graph.
    const int g0 = batch[elo >> 2];
    const int g1 = batch[(ehi - 1) >> 2];

    float base = 0.0f;

    if (g0 == g1) {
        float dot;
        if (ehi == elo + EBLK) {
            const float4* xa = x4 + elo + tid;
            const float4* ta = t4 + elo + tid;
            const float4 A0 = ldnt(xa + 0*BLOCK), A1 = ldnt(xa + 1*BLOCK),
                         A2 = ldnt(xa + 2*BLOCK), A3 = ldnt(xa + 3*BLOCK),
                         A4 = ldnt(xa + 4*BLOCK), A5 = ldnt(xa + 5*BLOCK),
                         A6 = ldnt(xa + 6*BLOCK), A7 = ldnt(xa + 7*BLOCK);
            const float4 C0 = ldnt(ta + 0*BLOCK), C1 = ldnt(ta + 1*BLOCK),
                         C2 = ldnt(ta + 2*BLOCK), C3 = ldnt(ta + 3*BLOCK),
                         C4 = ldnt(ta + 4*BLOCK), C5 = ldnt(ta + 5*BLOCK),
                         C6 = ldnt(ta + 6*BLOCK), C7 = ldnt(ta + 7*BLOCK);

            // 4 independent accumulation chains
            float d0 = A0.x*C0.x + A0.y*C0.y + A0.z*C0.z + A0.w*C0.w;
            float d1 = A1.x*C1.x + A1.y*C1.y + A1.z*C1.z + A1.w*C1.w;
            float d2 = A2.x*C2.x + A2.y*C2.y + A2.z*C2.z + A2.w*C2.w;
            float d3 = A3.x*C3.x + A3.y*C3.y + A3.z*C3.z + A3.w*C3.w;
            d0 += A4.x*C4.x + A4.y*C4.y + A4.z*C4.z + A4.w*C4.w;
            d1 += A5.x*C5.x + A5.y*C5.y + A5.z*C5.z + A5.w*C5.w;
            d2 += A6.x*C6.x + A6.y*C6.y + A6.z*C6.z + A6.w*C6.w;
            d3 += A7.x*C7.x + A7.y*C7.y + A7.z*C7.z + A7.w*C7.w;

            float b0 = A0.x*A0.x + A0.y*A0.y + A0.z*A0.z + A0.w*A0.w
                     + C0.x*C0.x + C0.y*C0.y + C0.z*C0.z + C0.w*C0.w;
            float b1 = A1.x*A1.x + A1.y*A1.y + A1.z*A1.z + A1.w*A1.w
                     + C1.x*C1.x + C1.y*C1.y + C1.z*C1.z + C1.w*C1.w;
            float b2 = A2.x*A2.x + A2.y*A2.y + A2.z*A2.z + A2.w*A2.w
                     + C2.x*C2.x + C2.y*C2.y + C2.z*C2.z + C2.w*C2.w;
            float b3 = A3.x*A3.x + A3.y*A3.y + A3.z*A3.z + A3.w*A3.w
                     + C3.x*C3.x + C3.y*C3.y + C3.z*C3.z + C3.w*C3.w;
            b0 += A4.x*A4.x + A4.y*A4.y + A4.z*A4.z + A4.w*A4.w
                + C4.x*C4.x + C4.y*C4.y + C4.z*C4.z + C4.w*C4.w;
            b1 += A5.x*A5.x + A5.y*A5.y + A5.z*A5.z + A5.w*A5.w
                + C5.x*C5.x + C5.y*C5.y + C5.z*C5.z + C5.w*C5.w;
            b2 += A6.x*A6.x + A6.y*A6.y + A6.z*A6.z + A6.w*A6.w
                + C6.x*C6.x + C6.y*C6.y + C6.z*C6.z + C6.w*C6.w;
            b3 += A7.x*A7.x + A7.y*A7.y + A7.z*A7.z + A7.w*A7.w
                + C7.x*C7.x + C7.y*C7.y + C7.z*C7.z + C7.w*C7.w;

            dot  = (d0 + d1) + (d2 + d3);
            base = (b0 + b1) + (b2 + b3);
        } else {
            // partial tail tile (at most one in the grid)
            dot = 0.0f;
            for (int e = elo + tid; e < ehi; e += BLOCK) {
                const float4 a = ldnt(x4 + e);
                const float4 c = ldnt(t4 + e);
                base += a.x*a.x + a.y*a.y + a.z*a.z + a.w*a.w
                      + c.x*c.x + c.y*c.y + c.z*c.z + c.w*c.w;
                dot  += a.x*c.x + a.y*c.y + a.z*c.z + a.w*c.w;
            }
        }
        #pragma unroll
        for (int off = 32; off > 0; off >>= 1) {
            dot  += __shfl_xor(dot,  off, 64);
            base += __shfl_xor(base, off, 64);
        }
        if ((tid & 63) == 0) {
            atomicAdd(&s_acc[g0], dot);
            atomicAdd(&s_acc[NGRAPH], base);
        }
    } else {
        // boundary tile (<=7 in the whole grid): per-element graph id + selects
        float acc[NGRAPH];
        #pragma unroll
        for (int i = 0; i < NGRAPH; ++i) acc[i] = 0.0f;
        for (int e = elo + tid; e < ehi; e += BLOCK) {
            const float4 a = ldnt(x4 + e);
            const float4 c = ldnt(t4 + e);
            const int    b = batch[e >> 2];
            base += a.x*a.x + a.y*a.y + a.z*a.z + a.w*a.w
                  + c.x*c.x + c.y*c.y + c.z*c.z + c.w*c.w;
            const float d = a.x*c.x + a.y*c.y + a.z*c.z + a.w*c.w;
            #pragma unroll
            for (int i = 0; i < NGRAPH; ++i)
                acc[i] += (b == i) ? d : 0.0f;
        }
        #pragma unroll
        for (int i = 0; i <= NGRAPH; ++i) {
            float v = (i < NGRAPH) ? acc[i] : base;
            #pragma unroll
            for (int off = 32; off > 0; off >>= 1)
                v += __shfl_xor(v, off, 64);
            if ((tid & 63) == 0)
                atomicAdd(&s_acc[i], v);
        }
    }
    __syncthreads();

    // spread global atomics over NSLOT distinct cachelines
    float* slot = g_acc + ((int)blockIdx.x & (NSLOT - 1)) * 16;
    if (tid <= NGRAPH)
        atomicAdd(&slot[tid], s_acc[tid]);
}

__global__ void finalize_kernel(const float* __restrict__ g_acc,
                                float* __restrict__ out)
{
    if (threadIdx.x == 0) {
        float dots[NGRAPH];
        #pragma unroll
        for (int i = 0; i < NGRAPH; ++i) dots[i] = 0.0f;
        float base = 0.0f;
        for (int s = 0; s < NSLOT; ++s) {
            #pragma unroll
            for (int i = 0; i < NGRAPH; ++i) dots[i] += g_acc[s * 16 + i];
            base += g_acc[s * 16 + NGRAPH];
        }
        float sum = 0.0f;
        #pragma unroll
        for (int i = 0; i < NGRAPH; ++i) sum += fabsf(dots[i]);
        out[0] = base - 2.0f * sum;
    }
}

extern "C" void kernel_launch(void* const* d_in, const int* in_sizes, int n_in,
                              void* d_out, int out_size, void* d_ws, size_t ws_size,
                              hipStream_t stream) {
    const float* inp   = (const float*)d_in[0];
    const float* tgt   = (const float*)d_in[1];
    const int*   batch = (const int*)d_in[2];
    // d_in[3] is batch_size == 8 (compile-time NGRAPH)

    const long long Nrows = (long long)in_sizes[0] / 16;  // F = 16
    const int       M     = (int)(Nrows * 4);             // float4 elements

    float* g_acc = (float*)d_ws;
    (void)hipMemsetAsync(g_acc, 0, NSLOT * 16 * sizeof(float), stream);

    const int nblocks = (M + EBLK - 1) / EBLK;            // one tile per block
    reduce_kernel<<<nblocks, BLOCK, 0, stream>>>(
        (const float4*)inp, (const float4*)tgt, batch, g_acc, M);

    finalize_kernel<<<1, 64, 0, stream>>>(g_acc, (float*)d_out);
}